// Round 16
// baseline (114.283 us; speedup 1.0000x reference)
//
#include <hip/hip_runtime.h>
#include <cstdint>
#include <cstddef>

typedef _Float16 half_t;
typedef __attribute__((ext_vector_type(8))) _Float16 f16x8;
typedef __attribute__((ext_vector_type(4))) _Float16 f16x4;
typedef __attribute__((ext_vector_type(4))) float f32x4;
typedef unsigned int uint_t;

// k-order: k = c*8 + i  (i innermost -> W-natural)
// Workspace offsets (bytes)
#define OFF_WH   0           // 1,474,560 f16 = 2,949,120
#define OFF_XHF  2949120     // 4,718,592
#define OFF_XKH  7667712     // 4,718,592
#define OFF_VHF  12386304    // 160*256 f16 = 81,920
#define OFF_LG   12468224    // 10u*1152c f32 = 46,080 (running raw logit sums)
#define OFF_CWH  12514304    // 10u*1152c f16 = 23,040 (softmax coeffs, g2-produced)
#define WS_NEED  12537344

// async 16B/lane global->LDS (lds dest = wave-uniform base + lane*16; global src per-lane)
__device__ __forceinline__ void gload16(const void* g, void* l) {
  __builtin_amdgcn_global_load_lds(
      (const __attribute__((address_space(1))) unsigned int*)g,
      (__attribute__((address_space(3))) unsigned int*)l, 16, 0, 0);
}

// ---------------- setup: wh + xhf + xkh + lg=0 (one launch, 3325 blocks) ----------------
__global__ void k_setup(const float* __restrict__ x, const float* __restrict__ W,
                        half_t* __restrict__ wh, half_t* __restrict__ xhf,
                        half_t* __restrict__ xkh, float* __restrict__ lg) {
  int bid = blockIdx.x, tid = threadIdx.x;
  if (bid < 720) {                       // wh: f16 copy of W, same linear layout
    int gid = bid * 256 + tid;           // 184320 x8-items
    const float4 a0 = *(const float4*)(W + (size_t)gid * 8);
    const float4 a1 = *(const float4*)(W + (size_t)gid * 8 + 4);
    f16x8 o;
    o[0] = (half_t)a0.x; o[1] = (half_t)a0.y; o[2] = (half_t)a0.z; o[3] = (half_t)a0.w;
    o[4] = (half_t)a1.x; o[5] = (half_t)a1.y; o[6] = (half_t)a1.z; o[7] = (half_t)a1.w;
    *(f16x8*)(wh + (size_t)gid * 8) = o;
  } else if (bid < 976) {                // xhf[b][c*8+i] = x[b][i][c], one block per b
    int b = bid - 720;
    __shared__ float lds_f[9216];
    const float4* xr = (const float4*)(x + (size_t)b * 9216);
    for (int t = tid; t < 2304; t += 256) {
      float4 v = xr[t];
      lds_f[t * 4 + 0] = v.x; lds_f[t * 4 + 1] = v.y;
      lds_f[t * 4 + 2] = v.z; lds_f[t * 4 + 3] = v.w;
    }
    __syncthreads();
    for (int t = tid; t < 1152; t += 256) {   // c = t, k chunk = c*8..c*8+7
      f16x8 o;
#pragma unroll
      for (int i = 0; i < 8; ++i) o[i] = (half_t)lds_f[i * 1152 + t];
      *(f16x8*)(xhf + (size_t)b * 9216 + t * 8) = o;
    }
  } else if (bid < 3280) {               // xkh[k][b] = x[b][i][c], 2304 tiles (32k x 32b)
    int tb = bid - 976;
    int kt = tb % 288, bt = tb / 288;
    int c0 = kt * 4, b0 = bt * 32;
    __shared__ float lt[32][36];
    int bl = tid >> 3, ch = tid & 7;     // b_local, i
    float4 v = *(const float4*)(x + (size_t)(b0 + bl) * 9216 + ch * 1152 + c0);
    lt[bl][0 * 8 + ch] = v.x;            // k_local = e*8 + i
    lt[bl][1 * 8 + ch] = v.y;
    lt[bl][2 * 8 + ch] = v.z;
    lt[bl][3 * 8 + ch] = v.w;
    __syncthreads();
    int kl = tid >> 3, bg = tid & 7;
    f16x4 h;
    h[0] = (half_t)lt[bg * 4 + 0][kl];
    h[1] = (half_t)lt[bg * 4 + 1][kl];
    h[2] = (half_t)lt[bg * 4 + 2][kl];
    h[3] = (half_t)lt[bg * 4 + 3][kl];
    *(f16x4*)(xkh + (size_t)(kt * 32 + kl) * 256 + b0 + bg * 4) = h;
  } else {                               // zero running logits (45 blocks, 11520)
    lg[(bid - 3280) * 256 + tid] = 0.f;
  }
}

// ---------------- G1+squash: 16 waves, 4-buffer async staging, XCD-swizzled grid ----------------
// grid (160), 1024 thr. Swizzle: XCD x owns mb {2x,2x+1} x all nt -> x/w L2-resident per XCD.
__global__ __launch_bounds__(1024) void k_g1sq(const half_t* __restrict__ xhf,
                                               const half_t* __restrict__ wh,
                                               const half_t* __restrict__ cwh,
                                               half_t* __restrict__ vhfT,
                                               float* __restrict__ out, int it) {
  int bid = blockIdx.x;
  int xcd = bid & 7, idx = bid >> 3;     // dispatch round-robins bid%8 -> XCD
  int mb = xcd * 2 + (idx & 1);          // bijective: 160 = 8 xcd * (2 mb-sub * 10 nt)
  int nt = idx >> 1;
  int tid = threadIdx.x;
  int wv = tid >> 6, l = tid & 63, lm = l & 15, lgp = l >> 4;
  __shared__ __align__(16) half_t cwf[1152];            // scalar cw[c] for column nt
  __shared__ __align__(16) half_t stage[16][4][2][512]; // [wave][buf][x/w][1KB] = 128KB
  __shared__ __align__(16) float red[16][64][4];

  // prologue: cw for this nt — g2-produced (it>0) or the uniform softmax(0)=0.1 (it==0)
  if (it == 0) {
    for (int c = tid; c < 1152; c += 1024) cwf[c] = (half_t)0.1f;
  } else {
    for (int c = tid; c < 1152; c += 1024) cwf[c] = cwh[(size_t)nt * 1152 + c];
  }
  __syncthreads();   // drains vmcnt -> counted waits below see only our loads

  // per-wave staging sources
  const half_t* xbase = xhf + (size_t)(mb * 16 + (l >> 2)) * 9216 + (l & 3) * 8;
  const half_t* wbase = wh + ((size_t)(lgp * 10 + nt) * 16 + lm) * 8;  // + kt*5120
  int kt0 = wv * 18;
  int cbase = kt0 * 4 + lgp;
#define ISSUE(J)                                                                   \
  do {                                                                             \
    int kt_ = kt0 + (J);                                                           \
    gload16(xbase + (size_t)kt_ * 32, &stage[wv][(J) % 4][0][0]);                  \
    gload16(wbase + (size_t)kt_ * 5120, &stage[wv][(J) % 4][1][0]);                \
  } while (0)

  ISSUE(0);
  ISSUE(1);
  ISSUE(2);
  ISSUE(3);   // 8 outstanding, 4 buffers (depth-3 prefetch)

  f32x4 acc0 = {0.f, 0.f, 0.f, 0.f};
  f32x4 acc1 = {0.f, 0.f, 0.f, 0.f};
#pragma unroll
  for (int j = 0; j < 18; ++j) {
    const int buf = j % 4;
    if (j <= 14) {
      asm volatile("s_waitcnt vmcnt(6)" ::: "memory");
    } else if (j == 15) {
      asm volatile("s_waitcnt vmcnt(4)" ::: "memory");
    } else if (j == 16) {
      asm volatile("s_waitcnt vmcnt(2)" ::: "memory");
    } else {
      asm volatile("s_waitcnt vmcnt(0)" ::: "memory");
    }
    __builtin_amdgcn_sched_barrier(0);
    f16x8 af = *(const f16x8*)&stage[wv][buf][0][lm * 32 + lgp * 8];
    f16x8 wf = *(const f16x8*)&stage[wv][buf][1][l * 8];
    half_t sc = cwf[cbase + j * 4];
    f16x8 bsc = wf * sc;
    if ((j & 1) == 0) acc0 = __builtin_amdgcn_mfma_f32_16x16x32_f16(af, bsc, acc0, 0, 0, 0);
    else              acc1 = __builtin_amdgcn_mfma_f32_16x16x32_f16(af, bsc, acc1, 0, 0, 0);
    __builtin_amdgcn_sched_barrier(0);
    // issue-after-consume: ds_reads of buf retired before MFMA -> refill race-free
    if (j + 4 < 18) ISSUE(j + 4);
    __builtin_amdgcn_sched_barrier(0);
  }
#undef ISSUE
  acc0[0] += acc1[0]; acc0[1] += acc1[1]; acc0[2] += acc1[2]; acc0[3] += acc1[3];
  *(f32x4*)&red[wv][l][0] = acc0;
  __syncthreads();
  if (wv == 0) {
    float4 s = make_float4(0.f, 0.f, 0.f, 0.f);
#pragma unroll
    for (int w = 0; w < 16; ++w) {
      s.x += red[w][l][0]; s.y += red[w][l][1];
      s.z += red[w][l][2]; s.w += red[w][l][3];
    }
    float4 n2 = make_float4(s.x * s.x, s.y * s.y, s.z * s.z, s.w * s.w);
#pragma unroll
    for (int off = 1; off < 16; off <<= 1) {   // sum over o (lm lanes)
      n2.x += __shfl_xor(n2.x, off);
      n2.y += __shfl_xor(n2.y, off);
      n2.z += __shfl_xor(n2.z, off);
      n2.w += __shfl_xor(n2.w, off);
    }
    float4 vv;
    vv.x = s.x * (n2.x / ((1.f + n2.x) * sqrtf(n2.x)));
    vv.y = s.y * (n2.y / ((1.f + n2.y) * sqrtf(n2.y)));
    vv.z = s.z * (n2.z / ((1.f + n2.z) * sqrtf(n2.z)));
    vv.w = s.w * (n2.w / ((1.f + n2.w) * sqrtf(n2.w)));
    if (it == 3) {   // rows b = mb*16 + lgp*4 + r, col = nt*16 + lm
      float* ob = out + (size_t)(mb * 16 + lgp * 4) * 160 + nt * 16 + lm;
      ob[0 * 160] = vv.x; ob[1 * 160] = vv.y; ob[2 * 160] = vv.z; ob[3 * 160] = vv.w;
    } else {         // vhfT[n][b]
      f16x4 h;
      h[0] = (half_t)vv.x; h[1] = (half_t)vv.y; h[2] = (half_t)vv.z; h[3] = (half_t)vv.w;
      *(f16x4*)(vhfT + (size_t)(nt * 16 + lm) * 256 + mb * 16 + lgp * 4) = h;
    }
  }
}

// ---------------- G2: agreement + logit update + softmax -> cwh (and lg) ----------------
// grid (144), 256 thr = 4 waves; wave = 1 mt tile (2 c's x 8 i), full b.
__global__ __launch_bounds__(256) void k_g2(const half_t* __restrict__ xkh,
                                            const half_t* __restrict__ vhfT,
                                            const float* __restrict__ W,
                                            float* __restrict__ lg,
                                            half_t* __restrict__ cwh) {
  int cb = blockIdx.x;
  int tid = threadIdx.x;
  int wv = tid >> 6, l = tid & 63, lm = l & 15, lgp = l >> 4;
  int mt = cb * 4 + wv;                 // 0..575
  __shared__ float sm[8][10];
  f32x4 z = {0.f, 0.f, 0.f, 0.f};
  f32x4 acc[10];
#pragma unroll
  for (int nt = 0; nt < 10; ++nt) acc[nt] = z;

#pragma unroll
  for (int bt = 0; bt < 8; ++bt) {
    f16x8 af = *(const f16x8*)(xkh + (size_t)(mt * 16 + lm) * 256 + bt * 32 + lgp * 8);
#pragma unroll
    for (int nt = 0; nt < 10; ++nt) {
      f16x8 bfr = *(const f16x8*)(vhfT + (size_t)(nt * 16 + lm) * 256 + bt * 32 + lgp * 8);
      acc[nt] = __builtin_amdgcn_mfma_f32_16x16x32_f16(af, bfr, acc[nt], 0, 0, 0);
    }
  }
  // epilogue: krow = mt*16 + lgp*4 + r -> c = mt*2 + (lgp>>1), i = (lgp&1)*4 + r
  int cc = mt * 2 + (lgp >> 1);
  int i0 = (lgp & 1) * 4;
  int cl = wv * 2 + (lgp >> 1);         // c_local 0..7
#pragma unroll
  for (int nt = 0; nt < 10; ++nt) {
    float4 wdv = *(const float4*)(W + ((size_t)(cc * 10 + nt) * 16 + lm) * 8 + i0);
    float q = acc[nt][0] * wdv.x + acc[nt][1] * wdv.y
            + acc[nt][2] * wdv.z + acc[nt][3] * wdv.w;
    q += __shfl_xor(q, 1);    // sum over o (lm)
    q += __shfl_xor(q, 2);
    q += __shfl_xor(q, 4);
    q += __shfl_xor(q, 8);
    q += __shfl_xor(q, 16);   // sum i-halves (lgp pairs)
    if (lm == 0 && (lgp & 1) == 0) sm[cl][nt] = q;
  }
  __syncthreads();
  if (tid < 8) {   // per-c: logits += ag (raw), softmax(lg/256) -> cwh
    int c = cb * 8 + tid;
    float lv[10];
    float mx = -1e30f;
#pragma unroll
    for (int u = 0; u < 10; ++u) {
      float nlg = lg[(size_t)u * 1152 + c] + sm[tid][u];
      lg[(size_t)u * 1152 + c] = nlg;
      lv[u] = nlg;
      mx = fmaxf(mx, nlg);
    }
    float ssum = 0.f;
#pragma unroll
    for (int u = 0; u < 10; ++u) {
      lv[u] = __expf((lv[u] - mx) * (1.0f / 256.0f));
      ssum += lv[u];
    }
    float inv = 1.f / ssum;
#pragma unroll
    for (int u = 0; u < 10; ++u)
      cwh[(size_t)u * 1152 + c] = (half_t)(lv[u] * inv);
  }
}

extern "C" void kernel_launch(void* const* d_in, const int* in_sizes, int n_in,
                              void* d_out, int out_size, void* d_ws, size_t ws_size,
                              hipStream_t stream) {
  const float* x = (const float*)d_in[0];
  const float* W = (const float*)d_in[1];
  float* out = (float*)d_out;
  char* ws = (char*)d_ws;
  if (ws_size < WS_NEED) return;   // output stays poisoned -> visible failure

  half_t* wh  = (half_t*)(ws + OFF_WH);
  half_t* xhf = (half_t*)(ws + OFF_XHF);
  half_t* xkh = (half_t*)(ws + OFF_XKH);
  half_t* vhfT= (half_t*)(ws + OFF_VHF);
  float*  lg  = (float*)(ws + OFF_LG);
  half_t* cwh = (half_t*)(ws + OFF_CWH);

  k_setup<<<dim3(3325), dim3(256), 0, stream>>>(x, W, wh, xhf, xkh, lg);
  for (int it = 0; it < 4; ++it) {
    k_g1sq<<<dim3(160), dim3(1024), 0, stream>>>(xhf, wh, cwh, vhfT, out, it);
    if (it < 3)
      k_g2<<<dim3(144), dim3(256), 0, stream>>>(xkh, vhfT, W, lg, cwh);
  }
}